// Round 5
// baseline (143.077 us; speedup 1.0000x reference)
//
#include <hip/hip_runtime.h>
#include <math.h>

#define KMAX 8
#define CSTRIDE 64   // ints between expert counters = 256 B -> distinct cache lines

typedef short s16x8 __attribute__((ext_vector_type(8)));
typedef float f32x4 __attribute__((ext_vector_type(4)));

__device__ inline ushort f2bf(float f) {
    union { float f; unsigned u; } v; v.f = f;
    unsigned r = v.u + 0x7fffu + ((v.u >> 16) & 1u);   // RNE
    return (ushort)(r >> 16);
}

__device__ inline void gload_lds16(const void* g, void* l) {
    __builtin_amdgcn_global_load_lds(
        (const __attribute__((address_space(1))) unsigned int*)g,
        (__attribute__((address_space(3))) unsigned int*)l, 16, 0, 0);
}

// ---------------------------------------------------------------------------
// K0: per-expert feature norms in double.  grid = E blocks of 64 threads.
// ---------------------------------------------------------------------------
__global__ void k_efnorm(const float* __restrict__ ef, int D,
                         double* __restrict__ efn) {
    int e = blockIdx.x;
    int lane = threadIdx.x;  // 64
    double s = 0.0;
    for (int i = lane; i < D; i += 64) {
        double v = (double)ef[(size_t)e * D + i];
        s = fma(v, v, s);
    }
    #pragma unroll
    for (int off = 32; off > 0; off >>= 1) s += __shfl_xor(s, off);
    if (lane == 0) efn[e] = sqrt(s);
}

// ---------------------------------------------------------------------------
// K1: x -> bf16 copy + per-token L2 norm (f64).  4 tokens/block, wave/token.
// ---------------------------------------------------------------------------
__global__ __launch_bounds__(256) void k_prep_x(
    const float* __restrict__ x, int D, ushort* __restrict__ xbf,
    double* __restrict__ xnorm) {
    int t = blockIdx.x * 4 + (threadIdx.x >> 6);
    int lane = threadIdx.x & 63;
    double s = 0.0;
    int nq = D / 256;
    for (int q = 0; q < nq; ++q) {
        float4 v = *(const float4*)&x[(size_t)t * D + q * 256 + lane * 4];
        ushort4 u;
        u.x = f2bf(v.x); u.y = f2bf(v.y); u.z = f2bf(v.z); u.w = f2bf(v.w);
        *(ushort4*)&xbf[(size_t)t * D + q * 256 + lane * 4] = u;
        double a = v.x, b = v.y, c = v.z, d = v.w;
        s = fma(a, a, fma(b, b, fma(c, c, fma(d, d, s))));
    }
    #pragma unroll
    for (int off = 32; off > 0; off >>= 1) s += __shfl_xor(s, off);
    if (lane == 0) xnorm[t] = sqrt(s);
}

// ---------------------------------------------------------------------------
// K2: W -> bf16, GATED on counts[e] > 0 (only ~4-6 experts are ever selected
// because scores are dominated by per-expert trust/staleness terms).
// grid = (nblk, E); each block converts 1024 float4 of expert e.
// ---------------------------------------------------------------------------
__global__ __launch_bounds__(256) void k_prep_w(
    const float* __restrict__ W, const int* __restrict__ counts,
    int perExpF4, ushort* __restrict__ wbf) {
    int e = blockIdx.y;
    if (counts[e * CSTRIDE] == 0) return;
    size_t base = (size_t)e * perExpF4;
    #pragma unroll
    for (int j = 0; j < 4; ++j) {
        int idx = (blockIdx.x * 4 + j) * 256 + threadIdx.x;
        if (idx < perExpF4) {
            float4 v = *(const float4*)&W[(base + idx) * 4];
            ushort4 u;
            u.x = f2bf(v.x); u.y = f2bf(v.y); u.z = f2bf(v.z); u.w = f2bf(v.w);
            *(ushort4*)&wbf[(base + idx) * 4] = u;
        }
    }
}

// ---------------------------------------------------------------------------
// K3: scores + top-k + scatter.  32 tokens/block, 256 threads, B/32 blocks.
// Dots: f32 FMA per 64-chunk, f64 accumulation across chunks (perturbation
// ~1e-9, proven tolerated by rounds 1-4).  Hierarchical scatter: LDS counters
// then one global atomicAdd per (block, expert) on 256B-spaced lines.
// ---------------------------------------------------------------------------
__global__ __launch_bounds__(256) void k_scores2(
    const float* __restrict__ x, const float* __restrict__ ef,
    const float* __restrict__ trust, const float* __restrict__ stale,
    const double* __restrict__ efn, const double* __restrict__ xnorm,
    const int* __restrict__ kp, int D, int B,
    int* __restrict__ counts, int* __restrict__ lists)
{
    __shared__ float xs[32 * 64];
    __shared__ float efs[32 * 64];
    __shared__ double sc[32 * 33];          // stride 33: conflict-free scan
    __shared__ int bcnt[32];
    __shared__ int bbase[32];
    __shared__ unsigned char selb[32 * KMAX];
    __shared__ unsigned char lposb[32 * KMAX];

    int tid = threadIdx.x;
    int tp = tid >> 4, eg = tid & 15;
    int tb = blockIdx.x * 32;
    int r0 = 2 * tp, r1 = 2 * tp + 1;
    int r0s = r0 & 15, r1s = r1 & 15;

    if (tid < 32) bcnt[tid] = 0;

    double accd[4] = {0, 0, 0, 0};
    int nch = D / 64;

    for (int ch = 0; ch < nch; ++ch) {
        #pragma unroll
        for (int t = 0; t < 2; ++t) {
            int id = t * 256 + tid;
            int r = id >> 4, q = id & 15;
            int sw = (q ^ (r & 15)) << 2;
            float4 v = *(const float4*)&x[(size_t)(tb + r) * D + ch * 64 + q * 4];
            *(float4*)&xs[r * 64 + sw] = v;
            float4 w = *(const float4*)&ef[(size_t)r * D + ch * 64 + q * 4];
            *(float4*)&efs[r * 64 + sw] = w;
        }
        __syncthreads();
        float a0 = 0.f, a1 = 0.f, a2 = 0.f, a3 = 0.f;
        #pragma unroll
        for (int q = 0; q < 16; ++q) {
            float4 xv0 = *(const float4*)&xs[r0 * 64 + ((q ^ r0s) << 2)];
            float4 xv1 = *(const float4*)&xs[r1 * 64 + ((q ^ r1s) << 2)];
            float4 e0 = *(const float4*)&efs[eg * 64 + ((q ^ eg) << 2)];
            float4 e1 = *(const float4*)&efs[(eg + 16) * 64 + ((q ^ eg) << 2)];
            a0 = fmaf(xv0.x, e0.x, a0); a0 = fmaf(xv0.y, e0.y, a0);
            a0 = fmaf(xv0.z, e0.z, a0); a0 = fmaf(xv0.w, e0.w, a0);
            a1 = fmaf(xv0.x, e1.x, a1); a1 = fmaf(xv0.y, e1.y, a1);
            a1 = fmaf(xv0.z, e1.z, a1); a1 = fmaf(xv0.w, e1.w, a1);
            a2 = fmaf(xv1.x, e0.x, a2); a2 = fmaf(xv1.y, e0.y, a2);
            a2 = fmaf(xv1.z, e0.z, a2); a2 = fmaf(xv1.w, e0.w, a2);
            a3 = fmaf(xv1.x, e1.x, a3); a3 = fmaf(xv1.y, e1.y, a3);
            a3 = fmaf(xv1.z, e1.z, a3); a3 = fmaf(xv1.w, e1.w, a3);
        }
        __syncthreads();
        accd[0] += (double)a0; accd[1] += (double)a1;
        accd[2] += (double)a2; accd[3] += (double)a3;
    }

    #pragma unroll
    for (int ti = 0; ti < 2; ++ti) {
        int t = tb + 2 * tp + ti;
        double xn = fmax(xnorm[t], 1e-8);
        #pragma unroll
        for (int ej = 0; ej < 2; ++ej) {
            int e = eg + 16 * ej;
            double en = fmax(efn[e], 1e-8);
            double cosv = accd[ti * 2 + ej] / (xn * en);
            sc[(2 * tp + ti) * 33 + e] = 0.4 * (double)trust[e]
                + 0.2 * (cosv + 1.0)
                + 0.2 * fmax(0.0, 1.0 - (double)stale[e]);
        }
    }
    __syncthreads();

    int kk = kp[0]; kk = kk < 1 ? 1 : (kk > KMAX ? KMAX : kk);

    // per-token top-k (strict > scan, lowest-index tie-break == jax.lax.top_k
    // selected set); record selection + LDS-local position
    if (tid < 32) {
        unsigned mask = 0;
        for (int p = 0; p < kk; ++p) {
            double bv = -1e300; int be = 0;
            #pragma unroll
            for (int e = 0; e < 32; ++e) {
                double v = sc[tid * 33 + e];
                if (!((mask >> e) & 1u) && v > bv) { bv = v; be = e; }
            }
            mask |= 1u << be;
            selb[tid * KMAX + p] = (unsigned char)be;
            lposb[tid * KMAX + p] = (unsigned char)atomicAdd(&bcnt[be], 1);
        }
    }
    __syncthreads();
    if (tid < 32) {
        int c = bcnt[tid];
        bbase[tid] = c ? atomicAdd(&counts[tid * CSTRIDE], c) : 0;
    }
    __syncthreads();
    if (tid < 32) {
        int t = tb + tid;
        for (int p = 0; p < kk; ++p) {
            int e = selb[tid * KMAX + p];
            lists[(size_t)e * B + bbase[e] + lposb[tid * KMAX + p]] = t;
        }
    }
}

// ---------------------------------------------------------------------------
// K4: grouped expert GEMM, bf16 MFMA, double-buffered global_load_lds with
// counted vmcnt (T3-minimum + T4): issue next K-tile's loads BEFORE computing
// the current one; wait vmcnt(8) (never 0 in-loop) + raw s_barrier so the
// prefetch stays in flight across the barrier (__syncthreads would drain it).
// grid = (ceil(B/128), C/128, E), 256 threads = 4 waves (2x2), BK=64.
// LDS 64.5 KB -> 2 blocks/CU.  XOR swizzle seg^=(row&7) on the per-lane
// global source + on ds_read (m201 both-sides pattern) -> 0 conflicts.
// ---------------------------------------------------------------------------
__global__ __launch_bounds__(256) void k_moe2(
    const ushort* __restrict__ xbf, const ushort* __restrict__ wbf,
    const float* __restrict__ bias, const int* __restrict__ lists,
    const int* __restrict__ counts, const int* __restrict__ kp,
    int B, int C, int D, float* __restrict__ out)
{
    int e = blockIdx.z;
    int cnt = counts[e * CSTRIDE];
    int row0 = blockIdx.x * 128;
    if (row0 >= cnt) return;            // uniform: safe before barriers
    int col0 = blockIdx.y * 128;
    int nt = min(128, cnt - row0);

    __shared__ ushort xsA[128 * 64], xsB[128 * 64];     // 16 KB each
    __shared__ ushort wshA[128 * 64], wshB[128 * 64];
    __shared__ int toks[128];

    int tid = threadIdx.x;
    if (tid < 128) toks[tid] = (tid < nt) ? lists[(size_t)e * B + row0 + tid] : 0;
    __syncthreads();

    int lane = tid & 63, wid = tid >> 6;
    int wr = wid >> 1, wc = wid & 1;    // wave tile: rows wr*64, cols wc*64
    int l15 = lane & 15, l16 = lane >> 4;

    f32x4 acc[4][4];
    #pragma unroll
    for (int m = 0; m < 4; ++m)
        #pragma unroll
        for (int n = 0; n < 4; ++n) acc[m][n] = (f32x4){0.f, 0.f, 0.f, 0.f};

    // 8 global_load_lds per wave per stage (4 x-tile + 4 w-tile, interleaved)
    auto STAGE = [&](ushort* bx, ushort* bw, int k0) {
        #pragma unroll
        for (int t = 0; t < 4; ++t) {
            int id = t * 256 + wid * 64 + lane;
            int r = id >> 3, seg = id & 7;
            int ssw = (seg ^ (r & 7)) << 3;
            gload_lds16(&xbf[(size_t)toks[r] * D + k0 + ssw],
                        (char*)bx + (t * 256 + wid * 64) * 16);
            gload_lds16(&wbf[((size_t)e * C + col0 + r) * D + k0 + ssw],
                        (char*)bw + (t * 256 + wid * 64) * 16);
        }
    };
    auto COMPUTE = [&](const ushort* bx, const ushort* bw) {
        #pragma unroll
        for (int ks = 0; ks < 2; ++ks) {
            s16x8 a[4], bfr[4];
            int sbase = ks * 4 + l16;
            #pragma unroll
            for (int m = 0; m < 4; ++m) {
                int r = wr * 64 + m * 16 + l15;
                a[m] = *(const s16x8*)&bx[r * 64 + ((sbase ^ (l15 & 7)) << 3)];
            }
            #pragma unroll
            for (int n = 0; n < 4; ++n) {
                int r = wc * 64 + n * 16 + l15;
                bfr[n] = *(const s16x8*)&bw[r * 64 + ((sbase ^ (l15 & 7)) << 3)];
            }
            #pragma unroll
            for (int m = 0; m < 4; ++m)
                #pragma unroll
                for (int n = 0; n < 4; ++n)
                    acc[m][n] = __builtin_amdgcn_mfma_f32_16x16x32_bf16(
                        a[m], bfr[n], acc[m][n], 0, 0, 0);
        }
    };

    int nch = D / 64;                    // even (D % 128 == 0)
    STAGE(xsA, wshA, 0);
    for (int ch = 0; ch < nch; ch += 2) {
        // ---- phase A: prefetch ch+1 into B, compute A ----
        if (ch + 1 < nch) {
            STAGE(xsB, wshB, (ch + 1) * 64);
            asm volatile("s_waitcnt vmcnt(8)" ::: "memory");
        } else {
            asm volatile("s_waitcnt vmcnt(0)" ::: "memory");
        }
        __builtin_amdgcn_s_barrier();
        __builtin_amdgcn_sched_barrier(0);
        COMPUTE(xsA, wshA);
        __builtin_amdgcn_s_barrier();
        // ---- phase B: prefetch ch+2 into A, compute B ----
        if (ch + 2 < nch) {
            STAGE(xsA, wshA, (ch + 2) * 64);
            asm volatile("s_waitcnt vmcnt(8)" ::: "memory");
        } else {
            asm volatile("s_waitcnt vmcnt(0)" ::: "memory");
        }
        __builtin_amdgcn_s_barrier();
        __builtin_amdgcn_sched_barrier(0);
        COMPUTE(xsB, wshB);
        __builtin_amdgcn_s_barrier();
    }

    int kk = kp[0]; kk = kk < 1 ? 1 : (kk > KMAX ? KMAX : kk);
    float invk = 1.0f / (float)kk;
    // C/D layout (m89): col = lane&15, row = (lane>>4)*4 + reg
    #pragma unroll
    for (int m = 0; m < 4; ++m) {
        int rbase = wr * 64 + m * 16 + l16 * 4;
        #pragma unroll
        for (int n = 0; n < 4; ++n) {
            int col = col0 + wc * 64 + n * 16 + l15;
            float bv = bias[(size_t)e * C + col];
            #pragma unroll
            for (int r = 0; r < 4; ++r) {
                int rl = rbase + r;
                if (rl < nt)
                    atomicAdd(&out[(size_t)toks[rl] * C + col],
                              invk * (acc[m][n][r] + bv));
            }
        }
    }
}

// ===========================================================================
// Legacy fallback — only if ws_size is too small for the bf16 mirrors.
// ===========================================================================
__global__ __launch_bounds__(256) void k_scores_legacy(
    const float* __restrict__ x, const float* __restrict__ ef,
    const float* __restrict__ trust, const float* __restrict__ stale,
    const double* __restrict__ efn, const int* __restrict__ kp,
    int D, int B, int* __restrict__ counts, int* __restrict__ lists)
{
    __shared__ float xs[32][72];
    __shared__ float efs[32][72];
    __shared__ double sc[32][33];

    int tid = threadIdx.x;
    int tl = tid >> 3, eg = tid & 7;
    int tb = blockIdx.x * 32;

    double acc[4] = {0, 0, 0, 0};
    double axx = 0.0;
    int nch = D / 64;

    for (int ch = 0; ch < nch; ++ch) {
        #pragma unroll
        for (int t = 0; t < 2; ++t) {
            int id = t * 256 + tid;
            int r = id >> 4, q = id & 15;
            float4 v = *(const float4*)&x[(size_t)(tb + r) * D + ch * 64 + q * 4];
            *(float4*)&xs[r][q * 4] = v;
            float4 w = *(const float4*)&ef[(size_t)r * D + ch * 64 + q * 4];
            *(float4*)&efs[r][q * 4] = w;
        }
        __syncthreads();
        #pragma unroll 4
        for (int q = 0; q < 16; ++q) {
            float4 xv = *(const float4*)&xs[tl][q * 4];
            double x0 = xv.x, x1 = xv.y, x2 = xv.z, x3 = xv.w;
            axx = fma(x0, x0, fma(x1, x1, fma(x2, x2, fma(x3, x3, axx))));
            #pragma unroll
            for (int j = 0; j < 4; ++j) {
                float4 ev = *(const float4*)&efs[eg + 8 * j][q * 4];
                acc[j] = fma(x0, (double)ev.x, acc[j]);
                acc[j] = fma(x1, (double)ev.y, acc[j]);
                acc[j] = fma(x2, (double)ev.z, acc[j]);
                acc[j] = fma(x3, (double)ev.w, acc[j]);
            }
        }
        __syncthreads();
    }

    double xn = fmax(sqrt(axx), 1e-8);
    #pragma unroll
    for (int j = 0; j < 4; ++j) {
        int e = eg + 8 * j;
        double en = fmax(efn[e], 1e-8);
        double cosv = acc[j] / (xn * en);
        sc[tl][e] = 0.4 * (double)trust[e] + 0.2 * (cosv + 1.0)
                  + 0.2 * fmax(0.0, 1.0 - (double)stale[e]);
    }
    __syncthreads();

    if (tid < 32) {
        int kk = kp[0]; kk = kk < 1 ? 1 : (kk > KMAX ? KMAX : kk);
        unsigned mask = 0;
        int t = tb + tid;
        for (int p = 0; p < kk; ++p) {
            double bv = -1e300; int be = 0;
            #pragma unroll
            for (int e = 0; e < 32; ++e) {
                double v = sc[tid][e];
                if (!((mask >> e) & 1u) && v > bv) { bv = v; be = e; }
            }
            mask |= 1u << be;
            int pos = atomicAdd(&counts[be * CSTRIDE], 1);
            lists[(size_t)be * B + pos] = t;
        }
    }
}

__global__ __launch_bounds__(512) void k_moe_f32(
    const float* __restrict__ x, const float* __restrict__ W,
    const float* __restrict__ bias, const int* __restrict__ lists,
    const int* __restrict__ counts, const int* __restrict__ kp,
    int B, int C, int D, float* __restrict__ out)
{
    int e = blockIdx.z;
    int cnt = counts[e * CSTRIDE];
    int row0 = blockIdx.x * 128;
    if (row0 >= cnt) return;
    int col0 = blockIdx.y * 256;
    int nt = min(128, cnt - row0);

    __shared__ ushort xs[128 * 72];
    __shared__ ushort wsh[256 * 72];
    __shared__ int toks[128];

    int tid = threadIdx.x;
    if (tid < 128) toks[tid] = (tid < nt) ? lists[(size_t)e * B + row0 + tid] : 0;
    __syncthreads();

    int lane = tid & 63, wid = tid >> 6;
    int wr = wid >> 2, wc = wid & 3;
    int l15 = lane & 15, l16 = lane >> 4;

    f32x4 acc[4][4];
    #pragma unroll
    for (int m = 0; m < 4; ++m)
        #pragma unroll
        for (int n = 0; n < 4; ++n) acc[m][n] = (f32x4){0.f, 0.f, 0.f, 0.f};

    int nch = D / 64;
    for (int ch = 0; ch < nch; ++ch) {
        int k0 = ch * 64;
        #pragma unroll
        for (int t = 0; t < 4; ++t) {
            int id = t * 512 + tid;
            int r = id >> 4, q = id & 15;
            float4 v = (r < nt)
                ? *(const float4*)&x[(size_t)toks[r] * D + k0 + q * 4]
                : make_float4(0.f, 0.f, 0.f, 0.f);
            ushort4 u;
            u.x = f2bf(v.x); u.y = f2bf(v.y); u.z = f2bf(v.z); u.w = f2bf(v.w);
            *(ushort4*)&xs[r * 72 + q * 4] = u;
        }
        #pragma unroll
        for (int t = 0; t < 8; ++t) {
            int id = t * 512 + tid;
            int r = id >> 4, q = id & 15;
            float4 v = *(const float4*)&W[((size_t)e * C + col0 + r) * D + k0 + q * 4];
            ushort4 u;
            u.x = f2bf(v.x); u.y = f2bf(v.y); u.z = f2bf(v.z); u.w = f2bf(v.w);
            *(ushort4*)&wsh[r * 72 + q * 4] = u;
        }
        __syncthreads();
        #pragma unroll
        for (int ks = 0; ks < 2; ++ks) {
            s16x8 a[4], bfr[4];
            #pragma unroll
            for (int m = 0; m < 4; ++m)
                a[m] = *(const s16x8*)&xs[(wr * 64 + m * 16 + l15) * 72 + ks * 32 + l16 * 8];
            #pragma unroll
            for (int n = 0; n < 4; ++n)
                bfr[n] = *(const s16x8*)&wsh[(wc * 64 + n * 16 + l15) * 72 + ks * 32 + l16 * 8];
            #pragma unroll
            for (int m = 0; m < 4; ++m)
                #pragma unroll
                for (int n = 0; n < 4; ++n)
                    acc[m][n] = __builtin_amdgcn_mfma_f32_16x16x32_bf16(
                        a[m], bfr[n], acc[m][n], 0, 0, 0);
        }
        __syncthreads();
    }

    int kk = kp[0]; kk = kk < 1 ? 1 : (kk > KMAX ? KMAX : kk);
    float invk = 1.0f / (float)kk;
    #pragma unroll
    for (int m = 0; m < 4; ++m) {
        int rbase = wr * 64 + m * 16 + l16 * 4;
        #pragma unroll
        for (int n = 0; n < 4; ++n) {
            int col = col0 + wc * 64 + n * 16 + l15;
            float bv = bias[(size_t)e * C + col];
            #pragma unroll
            for (int r = 0; r < 4; ++r) {
                int rl = rbase + r;
                if (rl < nt)
                    atomicAdd(&out[(size_t)toks[rl] * C + col],
                              invk * (acc[m][n][r] + bv));
            }
        }
    }
}

// ---------------------------------------------------------------------------
extern "C" void kernel_launch(void* const* d_in, const int* in_sizes, int n_in,
                              void* d_out, int out_size, void* d_ws, size_t ws_size,
                              hipStream_t stream) {
    const float* x     = (const float*)d_in[0];
    const float* ef    = (const float*)d_in[1];
    const float* trust = (const float*)d_in[2];
    const float* stale = (const float*)d_in[3];
    const float* W     = (const float*)d_in[4];
    const float* b     = (const float*)d_in[5];
    const int*   kp    = (const int*)d_in[6];

    int E = in_sizes[2];            // 32
    int D = in_sizes[1] / E;        // 1024
    int B = in_sizes[0] / D;        // 8192
    int C = in_sizes[5] / E;        // 256
    float* out = (float*)d_out;

    // workspace layout
    char* ws = (char*)d_ws;
    double* efn   = (double*)ws;                       // 256 B
    int*    counts= (int*)(ws + 256);                  // 32*CSTRIDE*4 = 8 KB
    size_t off_xn = 256 + 32 * CSTRIDE * 4;
    double* xnorm = (double*)(ws + off_xn);            // B*8
    size_t off_lists = off_xn + (size_t)B * 8;
    int*    lists = (int*)(ws + off_lists);            // E*B*4
    size_t off_xbf = off_lists + (size_t)E * B * 4;
    off_xbf = (off_xbf + 255) & ~(size_t)255;
    ushort* xbf = (ushort*)(ws + off_xbf);             // B*D*2
    size_t off_wbf = off_xbf + (size_t)B * D * 2;
    ushort* wbf = (ushort*)(ws + off_wbf);             // E*C*D*2
    size_t need = off_wbf + (size_t)E * C * D * 2;

    hipMemsetAsync(counts, 0, 32 * CSTRIDE * 4, stream);
    hipMemsetAsync(d_out, 0, (size_t)out_size * sizeof(float), stream);

    k_efnorm<<<E, 64, 0, stream>>>(ef, D, efn);

    if (ws_size >= need) {
        k_prep_x<<<B / 4, 256, 0, stream>>>(x, D, xbf, xnorm);
        k_scores2<<<B / 32, 256, 0, stream>>>(x, ef, trust, stale, efn, xnorm,
                                              kp, D, B, counts, lists);
        int perExpF4 = (C * D) / 4;
        dim3 wgrid((perExpF4 + 1023) / 1024, E);
        k_prep_w<<<wgrid, 256, 0, stream>>>(W, counts, perExpF4, wbf);
        dim3 grid((B + 127) / 128, C / 128, E);
        k_moe2<<<grid, 256, 0, stream>>>(xbf, wbf, b, lists, counts, kp,
                                         B, C, D, out);
    } else {
        k_scores_legacy<<<B / 32, 256, 0, stream>>>(x, ef, trust, stale, efn,
                                                    kp, D, B, counts, lists);
        dim3 grid((B + 127) / 128, C / 256, E);
        k_moe_f32<<<grid, 512, 0, stream>>>(x, W, b, lists, counts, kp,
                                            B, C, D, out);
    }
}

// Round 6
// 125.768 us; speedup vs baseline: 1.1376x; 1.1376x over previous
//
#include <hip/hip_runtime.h>
#include <math.h>

#define KMAX 8
#define CSTRIDE 64   // ints between expert counters = 256 B -> distinct cache lines

typedef short s16x8 __attribute__((ext_vector_type(8)));
typedef float f32x4 __attribute__((ext_vector_type(4)));

__device__ inline ushort f2bf(float f) {
    union { float f; unsigned u; } v; v.f = f;
    unsigned r = v.u + 0x7fffu + ((v.u >> 16) & 1u);   // RNE
    return (ushort)(r >> 16);
}

__device__ inline void gload_lds16(const void* g, void* l) {
    __builtin_amdgcn_global_load_lds(
        (const __attribute__((address_space(1))) unsigned int*)g,
        (__attribute__((address_space(3))) unsigned int*)l, 16, 0, 0);
}

// ---------------------------------------------------------------------------
// K0: per-expert feature norms in double.  grid = E blocks of 64 threads.
// ---------------------------------------------------------------------------
__global__ void k_efnorm(const float* __restrict__ ef, int D,
                         double* __restrict__ efn) {
    int e = blockIdx.x;
    int lane = threadIdx.x;  // 64
    double s = 0.0;
    for (int i = lane; i < D; i += 64) {
        double v = (double)ef[(size_t)e * D + i];
        s = fma(v, v, s);
    }
    #pragma unroll
    for (int off = 32; off > 0; off >>= 1) s += __shfl_xor(s, off);
    if (lane == 0) efn[e] = sqrt(s);
}

// ---------------------------------------------------------------------------
// K2: W -> bf16, GATED on counts[e] > 0 (scores are dominated by per-expert
// trust/staleness terms, so only a handful of experts are ever selected).
// ---------------------------------------------------------------------------
__global__ __launch_bounds__(256) void k_prep_w(
    const float* __restrict__ W, const int* __restrict__ counts,
    int perExpF4, ushort* __restrict__ wbf) {
    int e = blockIdx.y;
    if (counts[e * CSTRIDE] == 0) return;
    size_t base = (size_t)e * perExpF4;
    #pragma unroll
    for (int j = 0; j < 4; ++j) {
        int idx = (blockIdx.x * 4 + j) * 256 + threadIdx.x;
        if (idx < perExpF4) {
            float4 v = *(const float4*)&W[(base + idx) * 4];
            ushort4 u;
            u.x = f2bf(v.x); u.y = f2bf(v.y); u.z = f2bf(v.z); u.w = f2bf(v.w);
            *(ushort4*)&wbf[(base + idx) * 4] = u;
        }
    }
}

// ---------------------------------------------------------------------------
// K3: scores + top-k + scatter + x->bf16 mirror (prep_x fused into staging).
// 32 tokens/block, 256 threads, B/32 blocks.
// Dots: f32 FMA per 64-chunk, f64 accumulation across chunks; ||x||^2 in f64
// (same precision class as rounds 2-5 -> same selection behavior).
// Hierarchical scatter: LDS counters, then one global atomicAdd per
// (block, expert) on 256B-spaced lines (the round-4 fix for the 330 us
// same-cache-line atomic serialization).
// ---------------------------------------------------------------------------
__global__ __launch_bounds__(256) void k_scores2(
    const float* __restrict__ x, const float* __restrict__ ef,
    const float* __restrict__ trust, const float* __restrict__ stale,
    const double* __restrict__ efn, const int* __restrict__ kp,
    int D, int B, ushort* __restrict__ xbf,
    int* __restrict__ counts, int* __restrict__ lists)
{
    __shared__ float xs[32 * 64];
    __shared__ float efs[32 * 64];
    __shared__ double sc[32 * 33];          // stride 33: conflict-free scan
    __shared__ int bcnt[32];
    __shared__ int bbase[32];
    __shared__ unsigned char selb[32 * KMAX];
    __shared__ unsigned char lposb[32 * KMAX];

    int tid = threadIdx.x;
    int tp = tid >> 4, eg = tid & 15;
    int tb = blockIdx.x * 32;
    int r0 = 2 * tp, r1 = 2 * tp + 1;
    int r0s = r0 & 15, r1s = r1 & 15;

    if (tid < 32) bcnt[tid] = 0;

    double accd[4] = {0, 0, 0, 0};
    double axx0 = 0.0, axx1 = 0.0;
    int nch = D / 64;

    for (int ch = 0; ch < nch; ++ch) {
        #pragma unroll
        for (int t = 0; t < 2; ++t) {
            int id = t * 256 + tid;
            int r = id >> 4, q = id & 15;
            int sw = (q ^ (r & 15)) << 2;
            float4 v = *(const float4*)&x[(size_t)(tb + r) * D + ch * 64 + q * 4];
            *(float4*)&xs[r * 64 + sw] = v;
            // fused x -> bf16 mirror for the MFMA kernel
            ushort4 u;
            u.x = f2bf(v.x); u.y = f2bf(v.y); u.z = f2bf(v.z); u.w = f2bf(v.w);
            *(ushort4*)&xbf[(size_t)(tb + r) * D + ch * 64 + q * 4] = u;
            float4 w = *(const float4*)&ef[(size_t)r * D + ch * 64 + q * 4];
            *(float4*)&efs[r * 64 + sw] = w;
        }
        __syncthreads();
        float a0 = 0.f, a1 = 0.f, a2 = 0.f, a3 = 0.f;
        #pragma unroll
        for (int q = 0; q < 16; ++q) {
            float4 xv0 = *(const float4*)&xs[r0 * 64 + ((q ^ r0s) << 2)];
            float4 xv1 = *(const float4*)&xs[r1 * 64 + ((q ^ r1s) << 2)];
            float4 e0 = *(const float4*)&efs[eg * 64 + ((q ^ eg) << 2)];
            float4 e1 = *(const float4*)&efs[(eg + 16) * 64 + ((q ^ eg) << 2)];
            a0 = fmaf(xv0.x, e0.x, a0); a0 = fmaf(xv0.y, e0.y, a0);
            a0 = fmaf(xv0.z, e0.z, a0); a0 = fmaf(xv0.w, e0.w, a0);
            a1 = fmaf(xv0.x, e1.x, a1); a1 = fmaf(xv0.y, e1.y, a1);
            a1 = fmaf(xv0.z, e1.z, a1); a1 = fmaf(xv0.w, e1.w, a1);
            a2 = fmaf(xv1.x, e0.x, a2); a2 = fmaf(xv1.y, e0.y, a2);
            a2 = fmaf(xv1.z, e0.z, a2); a2 = fmaf(xv1.w, e0.w, a2);
            a3 = fmaf(xv1.x, e1.x, a3); a3 = fmaf(xv1.y, e1.y, a3);
            a3 = fmaf(xv1.z, e1.z, a3); a3 = fmaf(xv1.w, e1.w, a3);
            double d0x = xv0.x, d0y = xv0.y, d0z = xv0.z, d0w = xv0.w;
            double d1x = xv1.x, d1y = xv1.y, d1z = xv1.z, d1w = xv1.w;
            axx0 = fma(d0x, d0x, fma(d0y, d0y, fma(d0z, d0z, fma(d0w, d0w, axx0))));
            axx1 = fma(d1x, d1x, fma(d1y, d1y, fma(d1z, d1z, fma(d1w, d1w, axx1))));
        }
        __syncthreads();
        accd[0] += (double)a0; accd[1] += (double)a1;
        accd[2] += (double)a2; accd[3] += (double)a3;
    }

    double xn0 = fmax(sqrt(axx0), 1e-8);
    double xn1 = fmax(sqrt(axx1), 1e-8);
    #pragma unroll
    for (int ti = 0; ti < 2; ++ti) {
        double xn = ti ? xn1 : xn0;
        #pragma unroll
        for (int ej = 0; ej < 2; ++ej) {
            int e = eg + 16 * ej;
            double en = fmax(efn[e], 1e-8);
            double cosv = accd[ti * 2 + ej] / (xn * en);
            sc[(2 * tp + ti) * 33 + e] = 0.4 * (double)trust[e]
                + 0.2 * (cosv + 1.0)
                + 0.2 * fmax(0.0, 1.0 - (double)stale[e]);
        }
    }
    __syncthreads();

    int kk = kp[0]; kk = kk < 1 ? 1 : (kk > KMAX ? KMAX : kk);

    // per-token top-k (strict > scan, lowest-index tie-break == jax.lax.top_k
    // selected set); record selection + LDS-local position
    if (tid < 32) {
        unsigned mask = 0;
        for (int p = 0; p < kk; ++p) {
            double bv = -1e300; int be = 0;
            #pragma unroll
            for (int e = 0; e < 32; ++e) {
                double v = sc[tid * 33 + e];
                if (!((mask >> e) & 1u) && v > bv) { bv = v; be = e; }
            }
            mask |= 1u << be;
            selb[tid * KMAX + p] = (unsigned char)be;
            lposb[tid * KMAX + p] = (unsigned char)atomicAdd(&bcnt[be], 1);
        }
    }
    __syncthreads();
    if (tid < 32) {
        int c = bcnt[tid];
        bbase[tid] = c ? atomicAdd(&counts[tid * CSTRIDE], c) : 0;
    }
    __syncthreads();
    if (tid < 32) {
        int t = tb + tid;
        for (int p = 0; p < kk; ++p) {
            int e = selb[tid * KMAX + p];
            lists[(size_t)e * B + bbase[e] + lposb[tid * KMAX + p]] = t;
        }
    }
}

// ---------------------------------------------------------------------------
// K4: grouped expert GEMM, bf16 MFMA, global_load_lds staging.
// ROUND-4 single-buffer 2-barrier structure (round-5's explicit dbuf REGRESSED:
// 66 KB LDS halved blocks/CU; implicit cross-block wave overlap already hides
// stage latency — m99/m100/m132 reproduced).  BM 128->64 for ~2x more blocks
// (~1030, ~4/CU) to deepen that overlap; LDS 24.5 KB (6 blocks/CU cap).
// grid = (ceil(B/64), C/128, E), 256 threads = 4 waves (2x2), BK=64.
// XOR swizzle seg^=(row&7) on per-lane global source + on ds_read (m201
// both-sides pattern) -> 0 bank conflicts (verified round 4/5).
// ---------------------------------------------------------------------------
__global__ __launch_bounds__(256) void k_moe2(
    const ushort* __restrict__ xbf, const ushort* __restrict__ wbf,
    const float* __restrict__ bias, const int* __restrict__ lists,
    const int* __restrict__ counts, const int* __restrict__ kp,
    int B, int C, int D, float* __restrict__ out)
{
    int e = blockIdx.z;
    int cnt = counts[e * CSTRIDE];
    int row0 = blockIdx.x * 64;
    if (row0 >= cnt) return;            // uniform: safe before barriers
    int col0 = blockIdx.y * 128;
    int nt = min(64, cnt - row0);

    __shared__ ushort xs[64 * 64];      // 8 KB
    __shared__ ushort wsh[128 * 64];    // 16 KB
    __shared__ int toks[64];

    int tid = threadIdx.x;
    if (tid < 64) toks[tid] = (tid < nt) ? lists[(size_t)e * B + row0 + tid] : 0;
    __syncthreads();

    int lane = tid & 63, wid = tid >> 6;
    int wr = wid >> 1, wc = wid & 1;    // wave tile: rows wr*32, cols wc*64
    int l15 = lane & 15, l16 = lane >> 4;

    f32x4 acc[2][4];
    #pragma unroll
    for (int m = 0; m < 2; ++m)
        #pragma unroll
        for (int n = 0; n < 4; ++n) acc[m][n] = (f32x4){0.f, 0.f, 0.f, 0.f};

    int nch = D / 64;
    for (int ch = 0; ch < nch; ++ch) {
        int k0 = ch * 64;
        // x-tile: 64 rows x 8 segs = 512 ids, 2 per thread
        #pragma unroll
        for (int t = 0; t < 2; ++t) {
            int id = t * 256 + wid * 64 + lane;
            int r = id >> 3, seg = id & 7;
            int ssw = (seg ^ (r & 7)) << 3;
            gload_lds16(&xbf[(size_t)toks[r] * D + k0 + ssw],
                        (char*)xs + (size_t)id * 16 - (size_t)(lane * 16)
                                  + (size_t)(lane * 16));
        }
        // w-tile: 128 rows x 8 segs = 1024 ids, 4 per thread
        #pragma unroll
        for (int t = 0; t < 4; ++t) {
            int id = t * 256 + wid * 64 + lane;
            int r = id >> 3, seg = id & 7;
            int ssw = (seg ^ (r & 7)) << 3;
            gload_lds16(&wbf[((size_t)e * C + col0 + r) * D + k0 + ssw],
                        (char*)wsh + (size_t)id * 16);
        }
        __syncthreads();
        #pragma unroll
        for (int ks = 0; ks < 2; ++ks) {
            s16x8 a[2], bfr[4];
            int sbase = ks * 4 + l16;
            #pragma unroll
            for (int m = 0; m < 2; ++m) {
                int r = wr * 32 + m * 16 + l15;
                a[m] = *(const s16x8*)&xs[r * 64 + ((sbase ^ (l15 & 7)) << 3)];
            }
            #pragma unroll
            for (int n = 0; n < 4; ++n) {
                int r = wc * 64 + n * 16 + l15;
                bfr[n] = *(const s16x8*)&wsh[r * 64 + ((sbase ^ (l15 & 7)) << 3)];
            }
            #pragma unroll
            for (int m = 0; m < 2; ++m)
                #pragma unroll
                for (int n = 0; n < 4; ++n)
                    acc[m][n] = __builtin_amdgcn_mfma_f32_16x16x32_bf16(
                        a[m], bfr[n], acc[m][n], 0, 0, 0);
        }
        __syncthreads();
    }

    int kk = kp[0]; kk = kk < 1 ? 1 : (kk > KMAX ? KMAX : kk);
    float invk = 1.0f / (float)kk;
    // C/D layout (m89): col = lane&15, row = (lane>>4)*4 + reg
    #pragma unroll
    for (int m = 0; m < 2; ++m) {
        int rbase = wr * 32 + m * 16 + l16 * 4;
        #pragma unroll
        for (int n = 0; n < 4; ++n) {
            int col = col0 + wc * 64 + n * 16 + l15;
            float bv = bias[(size_t)e * C + col];
            #pragma unroll
            for (int r = 0; r < 4; ++r) {
                int rl = rbase + r;
                if (rl < nt)
                    atomicAdd(&out[(size_t)toks[rl] * C + col],
                              invk * (acc[m][n][r] + bv));
            }
        }
    }
}

// ===========================================================================
// Legacy fallback — only if ws_size is too small for the bf16 mirrors.
// ===========================================================================
__global__ __launch_bounds__(256) void k_scores_legacy(
    const float* __restrict__ x, const float* __restrict__ ef,
    const float* __restrict__ trust, const float* __restrict__ stale,
    const double* __restrict__ efn, const int* __restrict__ kp,
    int D, int B, int* __restrict__ counts, int* __restrict__ lists)
{
    __shared__ float xs[32][72];
    __shared__ float efs[32][72];
    __shared__ double sc[32][33];

    int tid = threadIdx.x;
    int tl = tid >> 3, eg = tid & 7;
    int tb = blockIdx.x * 32;

    double acc[4] = {0, 0, 0, 0};
    double axx = 0.0;
    int nch = D / 64;

    for (int ch = 0; ch < nch; ++ch) {
        #pragma unroll
        for (int t = 0; t < 2; ++t) {
            int id = t * 256 + tid;
            int r = id >> 4, q = id & 15;
            float4 v = *(const float4*)&x[(size_t)(tb + r) * D + ch * 64 + q * 4];
            *(float4*)&xs[r][q * 4] = v;
            float4 w = *(const float4*)&ef[(size_t)r * D + ch * 64 + q * 4];
            *(float4*)&efs[r][q * 4] = w;
        }
        __syncthreads();
        #pragma unroll 4
        for (int q = 0; q < 16; ++q) {
            float4 xv = *(const float4*)&xs[tl][q * 4];
            double x0 = xv.x, x1 = xv.y, x2 = xv.z, x3 = xv.w;
            axx = fma(x0, x0, fma(x1, x1, fma(x2, x2, fma(x3, x3, axx))));
            #pragma unroll
            for (int j = 0; j < 4; ++j) {
                float4 ev = *(const float4*)&efs[eg + 8 * j][q * 4];
                acc[j] = fma(x0, (double)ev.x, acc[j]);
                acc[j] = fma(x1, (double)ev.y, acc[j]);
                acc[j] = fma(x2, (double)ev.z, acc[j]);
                acc[j] = fma(x3, (double)ev.w, acc[j]);
            }
        }
        __syncthreads();
    }

    double xn = fmax(sqrt(axx), 1e-8);
    #pragma unroll
    for (int j = 0; j < 4; ++j) {
        int e = eg + 8 * j;
        double en = fmax(efn[e], 1e-8);
        double cosv = acc[j] / (xn * en);
        sc[tl][e] = 0.4 * (double)trust[e] + 0.2 * (cosv + 1.0)
                  + 0.2 * fmax(0.0, 1.0 - (double)stale[e]);
    }
    __syncthreads();

    if (tid < 32) {
        int kk = kp[0]; kk = kk < 1 ? 1 : (kk > KMAX ? KMAX : kk);
        unsigned mask = 0;
        int t = tb + tid;
        for (int p = 0; p < kk; ++p) {
            double bv = -1e300; int be = 0;
            #pragma unroll
            for (int e = 0; e < 32; ++e) {
                double v = sc[tid][e];
                if (!((mask >> e) & 1u) && v > bv) { bv = v; be = e; }
            }
            mask |= 1u << be;
            int pos = atomicAdd(&counts[be * CSTRIDE], 1);
            lists[(size_t)be * B + pos] = t;
        }
    }
}

__global__ __launch_bounds__(512) void k_moe_f32(
    const float* __restrict__ x, const float* __restrict__ W,
    const float* __restrict__ bias, const int* __restrict__ lists,
    const int* __restrict__ counts, const int* __restrict__ kp,
    int B, int C, int D, float* __restrict__ out)
{
    int e = blockIdx.z;
    int cnt = counts[e * CSTRIDE];
    int row0 = blockIdx.x * 128;
    if (row0 >= cnt) return;
    int col0 = blockIdx.y * 256;
    int nt = min(128, cnt - row0);

    __shared__ ushort xs[128 * 72];
    __shared__ ushort wsh[256 * 72];
    __shared__ int toks[128];

    int tid = threadIdx.x;
    if (tid < 128) toks[tid] = (tid < nt) ? lists[(size_t)e * B + row0 + tid] : 0;
    __syncthreads();

    int lane = tid & 63, wid = tid >> 6;
    int wr = wid >> 2, wc = wid & 3;
    int l15 = lane & 15, l16 = lane >> 4;

    f32x4 acc[4][4];
    #pragma unroll
    for (int m = 0; m < 4; ++m)
        #pragma unroll
        for (int n = 0; n < 4; ++n) acc[m][n] = (f32x4){0.f, 0.f, 0.f, 0.f};

    int nch = D / 64;
    for (int ch = 0; ch < nch; ++ch) {
        int k0 = ch * 64;
        #pragma unroll
        for (int t = 0; t < 4; ++t) {
            int id = t * 512 + tid;
            int r = id >> 4, q = id & 15;
            float4 v = (r < nt)
                ? *(const float4*)&x[(size_t)toks[r] * D + k0 + q * 4]
                : make_float4(0.f, 0.f, 0.f, 0.f);
            ushort4 u;
            u.x = f2bf(v.x); u.y = f2bf(v.y); u.z = f2bf(v.z); u.w = f2bf(v.w);
            *(ushort4*)&xs[r * 72 + q * 4] = u;
        }
        #pragma unroll
        for (int t = 0; t < 8; ++t) {
            int id = t * 512 + tid;
            int r = id >> 4, q = id & 15;
            float4 v = *(const float4*)&W[((size_t)e * C + col0 + r) * D + k0 + q * 4];
            ushort4 u;
            u.x = f2bf(v.x); u.y = f2bf(v.y); u.z = f2bf(v.z); u.w = f2bf(v.w);
            *(ushort4*)&wsh[r * 72 + q * 4] = u;
        }
        __syncthreads();
        #pragma unroll
        for (int ks = 0; ks < 2; ++ks) {
            s16x8 a[4], bfr[4];
            #pragma unroll
            for (int m = 0; m < 4; ++m)
                a[m] = *(const s16x8*)&xs[(wr * 64 + m * 16 + l15) * 72 + ks * 32 + l16 * 8];
            #pragma unroll
            for (int n = 0; n < 4; ++n)
                bfr[n] = *(const s16x8*)&wsh[(wc * 64 + n * 16 + l15) * 72 + ks * 32 + l16 * 8];
            #pragma unroll
            for (int m = 0; m < 4; ++m)
                #pragma unroll
                for (int n = 0; n < 4; ++n)
                    acc[m][n] = __builtin_amdgcn_mfma_f32_16x16x32_bf16(
                        a[m], bfr[n], acc[m][n], 0, 0, 0);
        }
        __syncthreads();
    }

    int kk = kp[0]; kk = kk < 1 ? 1 : (kk > KMAX ? KMAX : kk);
    float invk = 1.0f / (float)kk;
    #pragma unroll
    for (int m = 0; m < 4; ++m) {
        int rbase = wr * 64 + m * 16 + l16 * 4;
        #pragma unroll
        for (int n = 0; n < 4; ++n) {
            int col = col0 + wc * 64 + n * 16 + l15;
            float bv = bias[(size_t)e * C + col];
            #pragma unroll
            for (int r = 0; r < 4; ++r) {
                int rl = rbase + r;
                if (rl < nt)
                    atomicAdd(&out[(size_t)toks[rl] * C + col],
                              invk * (acc[m][n][r] + bv));
            }
        }
    }
}

// ---------------------------------------------------------------------------
extern "C" void kernel_launch(void* const* d_in, const int* in_sizes, int n_in,
                              void* d_out, int out_size, void* d_ws, size_t ws_size,
                              hipStream_t stream) {
    const float* x     = (const float*)d_in[0];
    const float* ef    = (const float*)d_in[1];
    const float* trust = (const float*)d_in[2];
    const float* stale = (const float*)d_in[3];
    const float* W     = (const float*)d_in[4];
    const float* b     = (const float*)d_in[5];
    const int*   kp    = (const int*)d_in[6];

    int E = in_sizes[2];            // 32
    int D = in_sizes[1] / E;        // 1024
    int B = in_sizes[0] / D;        // 8192
    int C = in_sizes[5] / E;        // 256
    float* out = (float*)d_out;

    // workspace layout
    char* ws = (char*)d_ws;
    double* efn   = (double*)ws;                       // 256 B
    int*    counts= (int*)(ws + 256);                  // 32*CSTRIDE*4 = 8 KB
    size_t off_lists = 256 + 32 * CSTRIDE * 4;
    int*    lists = (int*)(ws + off_lists);            // E*B*4
    size_t off_xbf = off_lists + (size_t)E * B * 4;
    off_xbf = (off_xbf + 255) & ~(size_t)255;
    ushort* xbf = (ushort*)(ws + off_xbf);             // B*D*2
    size_t off_wbf = off_xbf + (size_t)B * D * 2;
    ushort* wbf = (ushort*)(ws + off_wbf);             // E*C*D*2
    size_t need = off_wbf + (size_t)E * C * D * 2;

    hipMemsetAsync(counts, 0, 32 * CSTRIDE * 4, stream);
    hipMemsetAsync(d_out, 0, (size_t)out_size * sizeof(float), stream);

    k_efnorm<<<E, 64, 0, stream>>>(ef, D, efn);

    if (ws_size >= need) {
        k_scores2<<<B / 32, 256, 0, stream>>>(x, ef, trust, stale, efn,
                                              kp, D, B, xbf, counts, lists);
        int perExpF4 = (C * D) / 4;
        dim3 wgrid((perExpF4 + 1023) / 1024, E);
        k_prep_w<<<wgrid, 256, 0, stream>>>(W, counts, perExpF4, wbf);
        dim3 grid((B + 63) / 64, C / 128, E);
        k_moe2<<<grid, 256, 0, stream>>>(xbf, wbf, b, lists, counts, kp,
                                         B, C, D, out);
    } else {
        k_scores_legacy<<<B / 32, 256, 0, stream>>>(x, ef, trust, stale, efn,
                                                    kp, D, B, counts, lists);
        dim3 grid((B + 127) / 128, C / 256, E);
        k_moe_f32<<<grid, 512, 0, stream>>>(x, W, b, lists, counts, kp,
                                            B, C, D, out);
    }
}

// Round 7
// 101.076 us; speedup vs baseline: 1.4155x; 1.2443x over previous
//
#include <hip/hip_runtime.h>
#include <math.h>

#define KMAX 8
#define CSTRIDE 64   // ints between expert counters = 256 B -> distinct cache lines

typedef short s16x8 __attribute__((ext_vector_type(8)));
typedef float f32x4 __attribute__((ext_vector_type(4)));

__device__ inline ushort f2bf(float f) {
    union { float f; unsigned u; } v; v.f = f;
    unsigned r = v.u + 0x7fffu + ((v.u >> 16) & 1u);   // RNE
    return (ushort)(r >> 16);
}

__device__ inline void gload_lds16(const void* g, void* l) {
    __builtin_amdgcn_global_load_lds(
        (const __attribute__((address_space(1))) unsigned int*)g,
        (__attribute__((address_space(3))) unsigned int*)l, 16, 0, 0);
}

// ---------------------------------------------------------------------------
// K0: per-expert feature norms in double.  grid = E blocks of 64 threads.
// ---------------------------------------------------------------------------
__global__ void k_efnorm(const float* __restrict__ ef, int D,
                         double* __restrict__ efn) {
    int e = blockIdx.x;
    int lane = threadIdx.x;  // 64
    double s = 0.0;
    for (int i = lane; i < D; i += 64) {
        double v = (double)ef[(size_t)e * D + i];
        s = fma(v, v, s);
    }
    #pragma unroll
    for (int off = 32; off > 0; off >>= 1) s += __shfl_xor(s, off);
    if (lane == 0) efn[e] = sqrt(s);
}

// ---------------------------------------------------------------------------
// K2: W -> bf16, GATED on counts[e] > 0 (scores are dominated by per-expert
// trust/staleness terms, so only a handful of experts are ever selected).
// ---------------------------------------------------------------------------
__global__ __launch_bounds__(256) void k_prep_w(
    const float* __restrict__ W, const int* __restrict__ counts,
    int perExpF4, ushort* __restrict__ wbf) {
    int e = blockIdx.y;
    if (counts[e * CSTRIDE] == 0) return;
    size_t base = (size_t)e * perExpF4;
    #pragma unroll
    for (int j = 0; j < 4; ++j) {
        int idx = (blockIdx.x * 4 + j) * 256 + threadIdx.x;
        if (idx < perExpF4) {
            float4 v = *(const float4*)&W[(base + idx) * 4];
            ushort4 u;
            u.x = f2bf(v.x); u.y = f2bf(v.y); u.z = f2bf(v.z); u.w = f2bf(v.w);
            *(ushort4*)&wbf[(base + idx) * 4] = u;
        }
    }
}

// ---------------------------------------------------------------------------
// K3 v3: scores + top-k + scatter + x->bf16 mirror.
// 16 tokens/block, 256 threads, B/16 = 512 blocks (2 blocks/CU — round-6's
// 1 block/CU at VALUBusy 21% was pure latency starvation).
// T14 async-stage split: next chunk's x/ef loaded to REGISTERS before the
// current chunk's compute (global latency hides under the FMA phase), regs
// written to LDS after the barrier.  Thread (tp=tid>>4, eg=tid&15): token tp,
// experts {eg, eg+16}.  Dots + ||x||^2: f32 chains per 64-chunk, f64
// accumulation across chunks (score perturbation ~1e-9/4e-9 — tolerance
// proven by rounds 1-6).  Hierarchical scatter (round-4 fix) unchanged.
// ---------------------------------------------------------------------------
__global__ __launch_bounds__(256) void k_scores3(
    const float* __restrict__ x, const float* __restrict__ ef,
    const float* __restrict__ trust, const float* __restrict__ stale,
    const double* __restrict__ efn, const int* __restrict__ kp,
    int D, int B, ushort* __restrict__ xbf,
    int* __restrict__ counts, int* __restrict__ lists)
{
    __shared__ float xs[16 * 64];           // 4 KB
    __shared__ float efs[32 * 64];          // 8 KB
    __shared__ double sc[16 * 33];
    __shared__ int bcnt[32];
    __shared__ int bbase[32];
    __shared__ unsigned char selb[16 * KMAX];
    __shared__ unsigned char lposb[16 * KMAX];

    int tid = threadIdx.x;
    int tp = tid >> 4, eg = tid & 15;
    int tb = blockIdx.x * 16;

    if (tid < 32) bcnt[tid] = 0;

    // staging roles (1 x-float4 + 2 ef-float4 per thread per chunk)
    int rx = tid >> 4, qx = tid & 15;        // x rows 0..15
    int re0 = tid >> 4, re1 = 16 + (tid >> 4);  // ef rows 0..15 / 16..31
    int qe = tid & 15;

    int nch = D / 64;

    // preload chunk 0 into regs
    float4 vx  = *(const float4*)&x[(size_t)(tb + rx) * D + qx * 4];
    float4 ve0 = *(const float4*)&ef[(size_t)re0 * D + qe * 4];
    float4 ve1 = *(const float4*)&ef[(size_t)re1 * D + qe * 4];

    double acc0 = 0.0, acc1 = 0.0, axx = 0.0;

    for (int ch = 0; ch < nch; ++ch) {
        // write staged regs -> LDS (swizzled) + xbf mirror
        *(float4*)&xs[rx * 64 + ((qx ^ rx) << 2)] = vx;
        {
            ushort4 u;
            u.x = f2bf(vx.x); u.y = f2bf(vx.y); u.z = f2bf(vx.z); u.w = f2bf(vx.w);
            *(ushort4*)&xbf[(size_t)(tb + rx) * D + ch * 64 + qx * 4] = u;
        }
        *(float4*)&efs[re0 * 64 + ((qe ^ (re0 & 15)) << 2)] = ve0;
        *(float4*)&efs[re1 * 64 + ((qe ^ (re1 & 15)) << 2)] = ve1;
        __syncthreads();

        // issue NEXT chunk's loads before compute (T14: latency hides under FMA)
        if (ch + 1 < nch) {
            int k1 = (ch + 1) * 64;
            vx  = *(const float4*)&x[(size_t)(tb + rx) * D + k1 + qx * 4];
            ve0 = *(const float4*)&ef[(size_t)re0 * D + k1 + qe * 4];
            ve1 = *(const float4*)&ef[(size_t)re1 * D + k1 + qe * 4];
        }

        float a0 = 0.f, a1 = 0.f, ax = 0.f;
        #pragma unroll
        for (int q = 0; q < 16; ++q) {
            float4 xv = *(const float4*)&xs[tp * 64 + ((q ^ tp) << 2)];
            float4 e0 = *(const float4*)&efs[eg * 64 + ((q ^ eg) << 2)];
            float4 e1 = *(const float4*)&efs[(eg + 16) * 64 + ((q ^ eg) << 2)];
            a0 = fmaf(xv.x, e0.x, a0); a0 = fmaf(xv.y, e0.y, a0);
            a0 = fmaf(xv.z, e0.z, a0); a0 = fmaf(xv.w, e0.w, a0);
            a1 = fmaf(xv.x, e1.x, a1); a1 = fmaf(xv.y, e1.y, a1);
            a1 = fmaf(xv.z, e1.z, a1); a1 = fmaf(xv.w, e1.w, a1);
            ax = fmaf(xv.x, xv.x, ax); ax = fmaf(xv.y, xv.y, ax);
            ax = fmaf(xv.z, xv.z, ax); ax = fmaf(xv.w, xv.w, ax);
        }
        __syncthreads();
        acc0 += (double)a0; acc1 += (double)a1; axx += (double)ax;
    }

    double xn = fmax(sqrt(axx), 1e-8);
    {
        int e0i = eg;
        double en0 = fmax(efn[e0i], 1e-8);
        sc[tp * 33 + e0i] = 0.4 * (double)trust[e0i]
            + 0.2 * (acc0 / (xn * en0) + 1.0)
            + 0.2 * fmax(0.0, 1.0 - (double)stale[e0i]);
        int e1i = eg + 16;
        double en1 = fmax(efn[e1i], 1e-8);
        sc[tp * 33 + e1i] = 0.4 * (double)trust[e1i]
            + 0.2 * (acc1 / (xn * en1) + 1.0)
            + 0.2 * fmax(0.0, 1.0 - (double)stale[e1i]);
    }
    __syncthreads();

    int kk = kp[0]; kk = kk < 1 ? 1 : (kk > KMAX ? KMAX : kk);

    // per-token top-k (strict > scan, lowest-index tie-break == jax.lax.top_k
    // selected set); record selection + LDS-local position
    if (tid < 16) {
        unsigned mask = 0;
        for (int p = 0; p < kk; ++p) {
            double bv = -1e300; int be = 0;
            #pragma unroll
            for (int e = 0; e < 32; ++e) {
                double v = sc[tid * 33 + e];
                if (!((mask >> e) & 1u) && v > bv) { bv = v; be = e; }
            }
            mask |= 1u << be;
            selb[tid * KMAX + p] = (unsigned char)be;
            lposb[tid * KMAX + p] = (unsigned char)atomicAdd(&bcnt[be], 1);
        }
    }
    __syncthreads();
    if (tid < 32) {
        int c = bcnt[tid];
        bbase[tid] = c ? atomicAdd(&counts[tid * CSTRIDE], c) : 0;
    }
    __syncthreads();
    if (tid < 16) {
        int t = tb + tid;
        for (int p = 0; p < kk; ++p) {
            int e = selb[tid * KMAX + p];
            lists[(size_t)e * B + bbase[e] + lposb[tid * KMAX + p]] = t;
        }
    }
}

// ---------------------------------------------------------------------------
// K4: grouped expert GEMM, bf16 MFMA, global_load_lds staging.
// Round-4/6 single-buffer 2-barrier structure, BM=64 (LDS 24.5 KB, ~5
// blocks/CU; implicit cross-block wave overlap hides stage latency —
// explicit dbuf regressed in round 5).  grid = (ceil(B/64), C/128, E),
// 256 threads = 4 waves (2x2).  XOR swizzle seg^=(row&7) on per-lane global
// source + on ds_read (m201 both-sides) -> 0 bank conflicts (verified).
// ---------------------------------------------------------------------------
__global__ __launch_bounds__(256) void k_moe2(
    const ushort* __restrict__ xbf, const ushort* __restrict__ wbf,
    const float* __restrict__ bias, const int* __restrict__ lists,
    const int* __restrict__ counts, const int* __restrict__ kp,
    int B, int C, int D, float* __restrict__ out)
{
    int e = blockIdx.z;
    int cnt = counts[e * CSTRIDE];
    int row0 = blockIdx.x * 64;
    if (row0 >= cnt) return;            // uniform: safe before barriers
    int col0 = blockIdx.y * 128;
    int nt = min(64, cnt - row0);

    __shared__ ushort xs[64 * 64];      // 8 KB
    __shared__ ushort wsh[128 * 64];    // 16 KB
    __shared__ int toks[64];

    int tid = threadIdx.x;
    if (tid < 64) toks[tid] = (tid < nt) ? lists[(size_t)e * B + row0 + tid] : 0;
    __syncthreads();

    int lane = tid & 63, wid = tid >> 6;
    int wr = wid >> 1, wc = wid & 1;    // wave tile: rows wr*32, cols wc*64
    int l15 = lane & 15, l16 = lane >> 4;

    f32x4 acc[2][4];
    #pragma unroll
    for (int m = 0; m < 2; ++m)
        #pragma unroll
        for (int n = 0; n < 4; ++n) acc[m][n] = (f32x4){0.f, 0.f, 0.f, 0.f};

    int nch = D / 64;
    for (int ch = 0; ch < nch; ++ch) {
        int k0 = ch * 64;
        // x-tile: 64 rows x 8 segs = 512 ids, 2 per thread
        #pragma unroll
        for (int t = 0; t < 2; ++t) {
            int id = t * 256 + wid * 64 + lane;
            int r = id >> 3, seg = id & 7;
            int ssw = (seg ^ (r & 7)) << 3;
            gload_lds16(&xbf[(size_t)toks[r] * D + k0 + ssw],
                        (char*)xs + (size_t)(t * 256 + wid * 64) * 16);
        }
        // w-tile: 128 rows x 8 segs = 1024 ids, 4 per thread
        #pragma unroll
        for (int t = 0; t < 4; ++t) {
            int id = t * 256 + wid * 64 + lane;
            int r = id >> 3, seg = id & 7;
            int ssw = (seg ^ (r & 7)) << 3;
            gload_lds16(&wbf[((size_t)e * C + col0 + r) * D + k0 + ssw],
                        (char*)wsh + (size_t)(t * 256 + wid * 64) * 16);
        }
        __syncthreads();
        #pragma unroll
        for (int ks = 0; ks < 2; ++ks) {
            s16x8 a[2], bfr[4];
            int sbase = ks * 4 + l16;
            #pragma unroll
            for (int m = 0; m < 2; ++m) {
                int r = wr * 32 + m * 16 + l15;
                a[m] = *(const s16x8*)&xs[r * 64 + ((sbase ^ (l15 & 7)) << 3)];
            }
            #pragma unroll
            for (int n = 0; n < 4; ++n) {
                int r = wc * 64 + n * 16 + l15;
                bfr[n] = *(const s16x8*)&wsh[r * 64 + ((sbase ^ (l15 & 7)) << 3)];
            }
            #pragma unroll
            for (int m = 0; m < 2; ++m)
                #pragma unroll
                for (int n = 0; n < 4; ++n)
                    acc[m][n] = __builtin_amdgcn_mfma_f32_16x16x32_bf16(
                        a[m], bfr[n], acc[m][n], 0, 0, 0);
        }
        __syncthreads();
    }

    int kk = kp[0]; kk = kk < 1 ? 1 : (kk > KMAX ? KMAX : kk);
    float invk = 1.0f / (float)kk;
    // C/D layout (m89): col = lane&15, row = (lane>>4)*4 + reg
    #pragma unroll
    for (int m = 0; m < 2; ++m) {
        int rbase = wr * 32 + m * 16 + l16 * 4;
        #pragma unroll
        for (int n = 0; n < 4; ++n) {
            int col = col0 + wc * 64 + n * 16 + l15;
            float bv = bias[(size_t)e * C + col];
            #pragma unroll
            for (int r = 0; r < 4; ++r) {
                int rl = rbase + r;
                if (rl < nt)
                    atomicAdd(&out[(size_t)toks[rl] * C + col],
                              invk * (acc[m][n][r] + bv));
            }
        }
    }
}

// ===========================================================================
// Legacy fallback — only if ws_size is too small for the bf16 mirrors.
// ===========================================================================
__global__ __launch_bounds__(256) void k_scores_legacy(
    const float* __restrict__ x, const float* __restrict__ ef,
    const float* __restrict__ trust, const float* __restrict__ stale,
    const double* __restrict__ efn, const int* __restrict__ kp,
    int D, int B, int* __restrict__ counts, int* __restrict__ lists)
{
    __shared__ float xs[32][72];
    __shared__ float efs[32][72];
    __shared__ double sc[32][33];

    int tid = threadIdx.x;
    int tl = tid >> 3, eg = tid & 7;
    int tb = blockIdx.x * 32;

    double acc[4] = {0, 0, 0, 0};
    double axx = 0.0;
    int nch = D / 64;

    for (int ch = 0; ch < nch; ++ch) {
        #pragma unroll
        for (int t = 0; t < 2; ++t) {
            int id = t * 256 + tid;
            int r = id >> 4, q = id & 15;
            float4 v = *(const float4*)&x[(size_t)(tb + r) * D + ch * 64 + q * 4];
            *(float4*)&xs[r][q * 4] = v;
            float4 w = *(const float4*)&ef[(size_t)r * D + ch * 64 + q * 4];
            *(float4*)&efs[r][q * 4] = w;
        }
        __syncthreads();
        #pragma unroll 4
        for (int q = 0; q < 16; ++q) {
            float4 xv = *(const float4*)&xs[tl][q * 4];
            double x0 = xv.x, x1 = xv.y, x2 = xv.z, x3 = xv.w;
            axx = fma(x0, x0, fma(x1, x1, fma(x2, x2, fma(x3, x3, axx))));
            #pragma unroll
            for (int j = 0; j < 4; ++j) {
                float4 ev = *(const float4*)&efs[eg + 8 * j][q * 4];
                acc[j] = fma(x0, (double)ev.x, acc[j]);
                acc[j] = fma(x1, (double)ev.y, acc[j]);
                acc[j] = fma(x2, (double)ev.z, acc[j]);
                acc[j] = fma(x3, (double)ev.w, acc[j]);
            }
        }
        __syncthreads();
    }

    double xn = fmax(sqrt(axx), 1e-8);
    #pragma unroll
    for (int j = 0; j < 4; ++j) {
        int e = eg + 8 * j;
        double en = fmax(efn[e], 1e-8);
        double cosv = acc[j] / (xn * en);
        sc[tl][e] = 0.4 * (double)trust[e] + 0.2 * (cosv + 1.0)
                  + 0.2 * fmax(0.0, 1.0 - (double)stale[e]);
    }
    __syncthreads();

    if (tid < 32) {
        int kk = kp[0]; kk = kk < 1 ? 1 : (kk > KMAX ? KMAX : kk);
        unsigned mask = 0;
        int t = tb + tid;
        for (int p = 0; p < kk; ++p) {
            double bv = -1e300; int be = 0;
            #pragma unroll
            for (int e = 0; e < 32; ++e) {
                double v = sc[tid][e];
                if (!((mask >> e) & 1u) && v > bv) { bv = v; be = e; }
            }
            mask |= 1u << be;
            int pos = atomicAdd(&counts[be * CSTRIDE], 1);
            lists[(size_t)be * B + pos] = t;
        }
    }
}

__global__ __launch_bounds__(512) void k_moe_f32(
    const float* __restrict__ x, const float* __restrict__ W,
    const float* __restrict__ bias, const int* __restrict__ lists,
    const int* __restrict__ counts, const int* __restrict__ kp,
    int B, int C, int D, float* __restrict__ out)
{
    int e = blockIdx.z;
    int cnt = counts[e * CSTRIDE];
    int row0 = blockIdx.x * 128;
    if (row0 >= cnt) return;
    int col0 = blockIdx.y * 256;
    int nt = min(128, cnt - row0);

    __shared__ ushort xs[128 * 72];
    __shared__ ushort wsh[256 * 72];
    __shared__ int toks[128];

    int tid = threadIdx.x;
    if (tid < 128) toks[tid] = (tid < nt) ? lists[(size_t)e * B + row0 + tid] : 0;
    __syncthreads();

    int lane = tid & 63, wid = tid >> 6;
    int wr = wid >> 2, wc = wid & 3;
    int l15 = lane & 15, l16 = lane >> 4;

    f32x4 acc[4][4];
    #pragma unroll
    for (int m = 0; m < 4; ++m)
        #pragma unroll
        for (int n = 0; n < 4; ++n) acc[m][n] = (f32x4){0.f, 0.f, 0.f, 0.f};

    int nch = D / 64;
    for (int ch = 0; ch < nch; ++ch) {
        int k0 = ch * 64;
        #pragma unroll
        for (int t = 0; t < 4; ++t) {
            int id = t * 512 + tid;
            int r = id >> 4, q = id & 15;
            float4 v = (r < nt)
                ? *(const float4*)&x[(size_t)toks[r] * D + k0 + q * 4]
                : make_float4(0.f, 0.f, 0.f, 0.f);
            ushort4 u;
            u.x = f2bf(v.x); u.y = f2bf(v.y); u.z = f2bf(v.z); u.w = f2bf(v.w);
            *(ushort4*)&xs[r * 72 + q * 4] = u;
        }
        #pragma unroll
        for (int t = 0; t < 8; ++t) {
            int id = t * 512 + tid;
            int r = id >> 4, q = id & 15;
            float4 v = *(const float4*)&W[((size_t)e * C + col0 + r) * D + k0 + q * 4];
            ushort4 u;
            u.x = f2bf(v.x); u.y = f2bf(v.y); u.z = f2bf(v.z); u.w = f2bf(v.w);
            *(ushort4*)&wsh[r * 72 + q * 4] = u;
        }
        __syncthreads();
        #pragma unroll
        for (int ks = 0; ks < 2; ++ks) {
            s16x8 a[4], bfr[4];
            #pragma unroll
            for (int m = 0; m < 4; ++m)
                a[m] = *(const s16x8*)&xs[(wr * 64 + m * 16 + l15) * 72 + ks * 32 + l16 * 8];
            #pragma unroll
            for (int n = 0; n < 4; ++n)
                bfr[n] = *(const s16x8*)&wsh[(wc * 64 + n * 16 + l15) * 72 + ks * 32 + l16 * 8];
            #pragma unroll
            for (int m = 0; m < 4; ++m)
                #pragma unroll
                for (int n = 0; n < 4; ++n)
                    acc[m][n] = __builtin_amdgcn_mfma_f32_16x16x32_bf16(
                        a[m], bfr[n], acc[m][n], 0, 0, 0);
        }
        __syncthreads();
    }

    int kk = kp[0]; kk = kk < 1 ? 1 : (kk > KMAX ? KMAX : kk);
    float invk = 1.0f / (float)kk;
    #pragma unroll
    for (int m = 0; m < 4; ++m) {
        int rbase = wr * 64 + m * 16 + l16 * 4;
        #pragma unroll
        for (int n = 0; n < 4; ++n) {
            int col = col0 + wc * 64 + n * 16 + l15;
            float bv = bias[(size_t)e * C + col];
            #pragma unroll
            for (int r = 0; r < 4; ++r) {
                int rl = rbase + r;
                if (rl < nt)
                    atomicAdd(&out[(size_t)toks[rl] * C + col],
                              invk * (acc[m][n][r] + bv));
            }
        }
    }
}

// ---------------------------------------------------------------------------
extern "C" void kernel_launch(void* const* d_in, const int* in_sizes, int n_in,
                              void* d_out, int out_size, void* d_ws, size_t ws_size,
                              hipStream_t stream) {
    const float* x     = (const float*)d_in[0];
    const float* ef    = (const float*)d_in[1];
    const float* trust = (const float*)d_in[2];
    const float* stale = (const float*)d_in[3];
    const float* W     = (const float*)d_in[4];
    const float* b     = (const float*)d_in[5];
    const int*   kp    = (const int*)d_in[6];

    int E = in_sizes[2];            // 32
    int D = in_sizes[1] / E;        // 1024
    int B = in_sizes[0] / D;        // 8192
    int C = in_sizes[5] / E;        // 256
    float* out = (float*)d_out;

    // workspace layout
    char* ws = (char*)d_ws;
    double* efn   = (double*)ws;                       // 256 B
    int*    counts= (int*)(ws + 256);                  // 32*CSTRIDE*4 = 8 KB
    size_t off_lists = 256 + 32 * CSTRIDE * 4;
    int*    lists = (int*)(ws + off_lists);            // E*B*4
    size_t off_xbf = off_lists + (size_t)E * B * 4;
    off_xbf = (off_xbf + 255) & ~(size_t)255;
    ushort* xbf = (ushort*)(ws + off_xbf);             // B*D*2
    size_t off_wbf = off_xbf + (size_t)B * D * 2;
    ushort* wbf = (ushort*)(ws + off_wbf);             // E*C*D*2
    size_t need = off_wbf + (size_t)E * C * D * 2;

    hipMemsetAsync(counts, 0, 32 * CSTRIDE * 4, stream);
    hipMemsetAsync(d_out, 0, (size_t)out_size * sizeof(float), stream);

    k_efnorm<<<E, 64, 0, stream>>>(ef, D, efn);

    if (ws_size >= need) {
        k_scores3<<<B / 16, 256, 0, stream>>>(x, ef, trust, stale, efn,
                                              kp, D, B, xbf, counts, lists);
        int perExpF4 = (C * D) / 4;
        dim3 wgrid((perExpF4 + 1023) / 1024, E);
        k_prep_w<<<wgrid, 256, 0, stream>>>(W, counts, perExpF4, wbf);
        dim3 grid((B + 63) / 64, C / 128, E);
        k_moe2<<<grid, 256, 0, stream>>>(xbf, wbf, b, lists, counts, kp,
                                         B, C, D, out);
    } else {
        k_scores_legacy<<<B / 32, 256, 0, stream>>>(x, ef, trust, stale, efn,
                                                    kp, D, B, counts, lists);
        dim3 grid((B + 127) / 128, C / 256, E);
        k_moe_f32<<<grid, 512, 0, stream>>>(x, W, b, lists, counts, kp,
                                            B, C, D, out);
    }
}